// Round 18
// baseline (398.806 us; speedup 1.0000x reference)
//
#include <hip/hip_runtime.h>
#include <stdint.h>
#include <math.h>

// RNN predictor: B=2048, T=1024 teacher + FUT=64 AR, H=128.
// Round-18: chain surgery on R17 (391us, all-blocks-resident => wall =
// 1088 x single-chain step latency):
//  - o-MFMA uniform on ALL waves in both phases: removes the 12-vs-8 MFMA
//    wave-0 skew at every barrier (barrier waits for slowest wave).
//  - MFMA dep chains split depth-4 -> 2x depth-2 (+1 scalar add each; only
//    acc element [0] is consumed): ~2 MFMA latencies off the critical path.
//  - s_setprio(1) around the MFMA cluster (anti-phased blocks = the regime
//    where it measured positive).
//  - everything else byte-identical to R17: SPB=4, 4 waves, grid 512,
//    (256,2) = 2 anti-phased blocks/CU; single-fp16 weights; pi-permuted
//    LDS h layout + one ds_write_b32/lane; split teacher/AR loops; one
//    barrier/step; 64-entry o ring flushed as f32x4.

#define TLEN  1024
#define FUT   64
#define HID   128
#define SPB   4
#define NT    256
#define NSTEP (TLEN + FUT)

typedef float f32x4 __attribute__((ext_vector_type(4)));
typedef _Float16 f16x8 __attribute__((ext_vector_type(8)));
typedef uint32_t u32x4 __attribute__((ext_vector_type(4)));

__device__ __forceinline__ f16x8 asf16(u32x4 v) {
    return __builtin_bit_cast(f16x8, v);
}
__device__ __forceinline__ float fast_tanh(float v) {
    return 1.0f - 2.0f / (__expf(2.0f * v) + 1.0f);   // saturates correctly
}

__global__ __launch_bounds__(NT, 2) void rnn_kernel(
    const float* __restrict__ x,      // [B, T]
    const float* __restrict__ W_ih,   // [H, 1]
    const float* __restrict__ W_hh,   // [H, H]
    const float* __restrict__ b_ih,   // [H]
    const float* __restrict__ b_hh,   // [H]
    const float* __restrict__ W_out,  // [1, H]
    const float* __restrict__ b_out,  // [1]
    float* __restrict__ out)          // [B, T+FUT]
{
    // h: [p][row s=0..3][pi(k)] fp16, row 256B, byte ^= (s<<5) on reads/writes
    __shared__ __align__(16) unsigned short hbuf[2][SPB * HID];  // 2KB
    __shared__ __align__(16) float xstg[128][8];                 // cols 0..3
    __shared__ __align__(16) float ring[2][SPB][68];             // o ring

    const int tid  = threadIdx.x;
    const int lane = tid & 63;
    const int wid  = tid >> 6;        // wave w: cols 32w..32w+31
    const int l15  = lane & 15;
    const int g    = lane >> 4;       // = sample index in epilogue
    const int s0   = blockIdx.x * SPB;

    // ---- weight B-fragments, single fp16; pi: slot(kt,g,e) -> k=16e+4kt+g
    const int j0 = 32 * wid + l15;
    const int j1 = j0 + 16;
    f16x8 W0[4], W1[4], Wo[4];
    {
        const float* r0 = W_hh + (size_t)j0 * HID;
        const float* r1 = W_hh + (size_t)j1 * HID;
        #pragma unroll
        for (int kt = 0; kt < 4; ++kt) {
            #pragma unroll
            for (int e = 0; e < 8; ++e) {
                const int k = 16 * e + 4 * kt + g;
                W0[kt][e] = (_Float16)r0[k];
                W1[kt][e] = (_Float16)r1[k];
                Wo[kt][e] = (l15 == 0) ? (_Float16)W_out[k] : (_Float16)0.0f;
            }
        }
    }
    const float bias0 = b_ih[j0] + b_hh[j0];
    const float bias1 = b_ih[j1] + b_hh[j1];
    const float wih0  = W_ih[j0], wih1 = W_ih[j1];
    const float bo    = b_out[0];

    // ---- LDS byte offsets (R11/R17-verified) ----
    const int s_ = l15 >> 2;          // A row, active lanes l15&3==0
    int aoff[4];
    #pragma unroll
    for (int kt = 0; kt < 4; ++kt)
        aoff[kt] = s_ * 256 + (((4 * kt + g) * 16) ^ (s_ << 5));
    const int woff = g * 256 + ((l15 * 16 + wid * 4) ^ (g << 5));

    for (int idx = tid; idx < SPB * HID; idx += NT)   // both parities (u32)
        ((uint32_t*)hbuf)[idx] = 0;
    __syncthreads();

    // A-frags zeroed once; masked loads keep inactive lanes at zero.
    u32x4 A_[4];
    #pragma unroll
    for (int kt = 0; kt < 4; ++kt) A_[kt] = (u32x4){0, 0, 0, 0};

// 12 MFMA, 6 independent depth-2 chains; scalar combines of element [0].
#define MFMA_BLOCK(SA, SB, OO)                                               \
    f32x4 zz = {0.f,0.f,0.f,0.f};                                            \
    f32x4 sA0 = zz, sA1 = zz, sB0 = zz, sB1 = zz, ov0 = zz, ov1 = zz;        \
    __builtin_amdgcn_s_setprio(1);                                           \
    sA0 = __builtin_amdgcn_mfma_f32_16x16x32_f16(asf16(A_[0]), W0[0], sA0, 0, 0, 0); \
    sB0 = __builtin_amdgcn_mfma_f32_16x16x32_f16(asf16(A_[0]), W1[0], sB0, 0, 0, 0); \
    ov0 = __builtin_amdgcn_mfma_f32_16x16x32_f16(asf16(A_[0]), Wo[0], ov0, 0, 0, 0); \
    sA1 = __builtin_amdgcn_mfma_f32_16x16x32_f16(asf16(A_[2]), W0[2], sA1, 0, 0, 0); \
    sB1 = __builtin_amdgcn_mfma_f32_16x16x32_f16(asf16(A_[2]), W1[2], sB1, 0, 0, 0); \
    ov1 = __builtin_amdgcn_mfma_f32_16x16x32_f16(asf16(A_[2]), Wo[2], ov1, 0, 0, 0); \
    sA0 = __builtin_amdgcn_mfma_f32_16x16x32_f16(asf16(A_[1]), W0[1], sA0, 0, 0, 0); \
    sB0 = __builtin_amdgcn_mfma_f32_16x16x32_f16(asf16(A_[1]), W1[1], sB0, 0, 0, 0); \
    ov0 = __builtin_amdgcn_mfma_f32_16x16x32_f16(asf16(A_[1]), Wo[1], ov0, 0, 0, 0); \
    sA1 = __builtin_amdgcn_mfma_f32_16x16x32_f16(asf16(A_[3]), W0[3], sA1, 0, 0, 0); \
    sB1 = __builtin_amdgcn_mfma_f32_16x16x32_f16(asf16(A_[3]), W1[3], sB1, 0, 0, 0); \
    ov1 = __builtin_amdgcn_mfma_f32_16x16x32_f16(asf16(A_[3]), Wo[3], ov1, 0, 0, 0); \
    __builtin_amdgcn_s_setprio(0);                                           \
    const float SA = sA0[0] + sA1[0];                                        \
    const float SB = sB0[0] + sB1[0];                                        \
    const float OO = ov0[0] + ov1[0] + bo;

    // ================= teacher-forced loop =================
    #pragma unroll 2
    for (int i = 0; i < TLEN; ++i) {
        const int p = i & 1;

        if ((i & 127) == 0) {         // refill x chunk (coalesced along t)
            #pragma unroll
            for (int pass = 0; pass < 2; ++pass) {
                const int idx = pass * NT + tid;
                const int t = idx & 127, s = idx >> 7;
                xstg[t][s] = x[(size_t)(s0 + s) * TLEN + (i + t)];
            }
            __syncthreads();
        }
        if (i > 64 && (i & 63) == 1 && tid < 16 * SPB) {   // flush o ring
            const int q = ((i - 65) >> 6) & 1;
            const int s = tid >> 4, c4 = (tid & 15) * 4;
            const f32x4 v = *(const f32x4*)&ring[q][s][c4];
            *(f32x4*)&out[(size_t)(s0 + s) * NSTEP + (i - 65) + c4] = v;
        }

        const char* hb = (const char*)hbuf[p];
        if ((l15 & 3) == 0) {
            #pragma unroll
            for (int kt = 0; kt < 4; ++kt)
                A_[kt] = *(const u32x4*)(hb + aoff[kt]);
        }

        MFMA_BLOCK(sa, sb, oo)

        // o_{i-1}[sample g] at wave-0 lanes l15==0 (C row 4g, col 0)
        if (i > 0 && wid == 0 && l15 == 0)
            ring[((i - 1) >> 6) & 1][g][(i - 1) & 63] = oo;

        const float in = xstg[i & 127][g];
        const float h0 = fast_tanh(sa + bias0 + in * wih0);
        const float h1 = fast_tanh(sb + bias1 + in * wih1);
        const uint32_t pv = (uint32_t)__builtin_bit_cast(unsigned short, (_Float16)h0)
                          | ((uint32_t)__builtin_bit_cast(unsigned short, (_Float16)h1) << 16);
        *(uint32_t*)((char*)hbuf[p ^ 1] + woff) = pv;

        __syncthreads();
    }

    // ================= autoregressive loop =================
    #pragma unroll 2
    for (int i = TLEN; i < NSTEP; ++i) {
        const int p = i & 1;

        if ((i & 63) == 1 && tid < 16 * SPB) {   // flush (fires at i=1025)
            const int q = ((i - 65) >> 6) & 1;
            const int s = tid >> 4, c4 = (tid & 15) * 4;
            const f32x4 v = *(const f32x4*)&ring[q][s][c4];
            *(f32x4*)&out[(size_t)(s0 + s) * NSTEP + (i - 65) + c4] = v;
        }

        const char* hb = (const char*)hbuf[p];
        if ((l15 & 3) == 0) {
            #pragma unroll
            for (int kt = 0; kt < 4; ++kt)
                A_[kt] = *(const u32x4*)(hb + aoff[kt]);
        }

        MFMA_BLOCK(sa, sb, oval)

        if (wid == 0 && l15 == 0)
            ring[((i - 1) >> 6) & 1][g][(i - 1) & 63] = oval;

        // feedback: sample g's o sits at lane g*16 (reg 0)
        const float in = __shfl(oval, g << 4);
        const float h0 = fast_tanh(sa + bias0 + in * wih0);
        const float h1 = fast_tanh(sb + bias1 + in * wih1);
        const uint32_t pv = (uint32_t)__builtin_bit_cast(unsigned short, (_Float16)h0)
                          | ((uint32_t)__builtin_bit_cast(unsigned short, (_Float16)h1) << 16);
        *(uint32_t*)((char*)hbuf[p ^ 1] + woff) = pv;

        __syncthreads();
    }

    // tail: o_{NSTEP-1} = wout . h_{NSTEP} (state in hbuf[NSTEP&1] = [0])
    {
        const char* hb = (const char*)hbuf[NSTEP & 1];
        if ((l15 & 3) == 0) {
            #pragma unroll
            for (int kt = 0; kt < 4; ++kt)
                A_[kt] = *(const u32x4*)(hb + aoff[kt]);
        }
        f32x4 ov = {0.f,0.f,0.f,0.f};
        #pragma unroll
        for (int kt = 0; kt < 4; ++kt)
            ov = __builtin_amdgcn_mfma_f32_16x16x32_f16(asf16(A_[kt]), Wo[kt], ov, 0, 0, 0);
        if (wid == 0 && l15 == 0)
            ring[0][g][63] = ov[0] + bo;        // (1087>>6)&1 = 0
    }
    __syncthreads();
    if (tid < 16 * SPB) {   // flush t = 1024..1087 (ring parity 0)
        const int s = tid >> 4, c4 = (tid & 15) * 4;
        const f32x4 v = *(const f32x4*)&ring[0][s][c4];
        *(f32x4*)&out[(size_t)(s0 + s) * NSTEP + TLEN + c4] = v;
    }
}

extern "C" void kernel_launch(void* const* d_in, const int* in_sizes, int n_in,
                              void* d_out, int out_size, void* d_ws, size_t ws_size,
                              hipStream_t stream) {
    const float* x     = (const float*)d_in[0];
    const float* W_ih  = (const float*)d_in[1];
    const float* W_hh  = (const float*)d_in[2];
    const float* b_ih  = (const float*)d_in[3];
    const float* b_hh  = (const float*)d_in[4];
    const float* W_out = (const float*)d_in[5];
    const float* b_out = (const float*)d_in[6];
    float* out = (float*)d_out;

    dim3 grid(2048 / SPB);   // 512 blocks -> 2 per CU, all resident
    dim3 block(NT);
    rnn_kernel<<<grid, block, 0, stream>>>(x, W_ih, W_hh, b_ih, b_hh,
                                           W_out, b_out, out);
}

// Round 19
// 395.002 us; speedup vs baseline: 1.0096x; 1.0096x over previous
//
#include <hip/hip_runtime.h>
#include <stdint.h>
#include <math.h>

// RNN predictor: B=2048, T=1024 teacher + FUT=64 AR, H=128.
// Round-19: R17's step (391us) with 8 THIN waves instead of 4 heavy ones.
//  - SPB=4, NT=512 (8 waves), grid=512, __launch_bounds__(512,4):
//    2 blocks/CU -> 16 waves/CU -> 4 chains interleaved per SIMD.
//  - wave w owns ONE 16-col j-tile (j = 16w + l15): 4 S-MFMA + 4 o-MFMA
//    (uniform on all waves -> zero skew; AR needs o everywhere anyway),
//    ONE tanh + ONE ds_write_b16 per lane. Per-wave issue ~halved vs R17.
//  - single-fp16 weights (W 16 regs + Wo 16 regs), pi-permuted LDS h layout
//    (slot(kt,g,e) -> k = 16e+4kt+g), masked 4x ds_read_b128 A-reads,
//    one barrier/step, split teacher/AR loops, 64-entry o ring.
//  - h'-write: lane (g,l15) -> row g, byte l15*16 + 2*wid, XOR (g<<5):
//    <=2-way banks (audited).

#define TLEN  1024
#define FUT   64
#define HID   128
#define SPB   4
#define NT    512
#define NSTEP (TLEN + FUT)

typedef float f32x4 __attribute__((ext_vector_type(4)));
typedef _Float16 f16x8 __attribute__((ext_vector_type(8)));
typedef uint32_t u32x4 __attribute__((ext_vector_type(4)));

__device__ __forceinline__ f16x8 asf16(u32x4 v) {
    return __builtin_bit_cast(f16x8, v);
}
__device__ __forceinline__ float fast_tanh(float v) {
    return 1.0f - 2.0f / (__expf(2.0f * v) + 1.0f);   // saturates correctly
}

__global__ __launch_bounds__(NT, 4) void rnn_kernel(
    const float* __restrict__ x,      // [B, T]
    const float* __restrict__ W_ih,   // [H, 1]
    const float* __restrict__ W_hh,   // [H, H]
    const float* __restrict__ b_ih,   // [H]
    const float* __restrict__ b_hh,   // [H]
    const float* __restrict__ W_out,  // [1, H]
    const float* __restrict__ b_out,  // [1]
    float* __restrict__ out)          // [B, T+FUT]
{
    // h: [p][row s=0..3][pi(k)] fp16, row 256B, byte ^= (s<<5) on both sides
    __shared__ __align__(16) unsigned short hbuf[2][SPB * HID];  // 2KB
    __shared__ __align__(16) float xstg[128][8];                 // cols 0..3
    __shared__ __align__(16) float ring[2][SPB][68];             // o ring

    const int tid  = threadIdx.x;
    const int lane = tid & 63;
    const int wid  = tid >> 6;        // wave w: j-tile cols 16w..16w+15
    const int l15  = lane & 15;
    const int g    = lane >> 4;       // = sample index in epilogue
    const int s0   = blockIdx.x * SPB;

    // ---- weight B-fragments, single fp16; pi: slot(kt,g,e) -> k=16e+4kt+g
    const int j = 16 * wid + l15;
    f16x8 W0[4], Wo[4];
    {
        const float* r0 = W_hh + (size_t)j * HID;
        #pragma unroll
        for (int kt = 0; kt < 4; ++kt) {
            #pragma unroll
            for (int e = 0; e < 8; ++e) {
                const int k = 16 * e + 4 * kt + g;
                W0[kt][e] = (_Float16)r0[k];
                Wo[kt][e] = (l15 == 0) ? (_Float16)W_out[k] : (_Float16)0.0f;
            }
        }
    }
    const float bias0 = b_ih[j] + b_hh[j];
    const float wih0  = W_ih[j];
    const float bo    = b_out[0];

    // ---- LDS byte offsets ----
    const int s_ = l15 >> 2;          // A row, active lanes l15&3==0
    int aoff[4];
    #pragma unroll
    for (int kt = 0; kt < 4; ++kt)
        aoff[kt] = s_ * 256 + (((4 * kt + g) * 16) ^ (s_ << 5));
    // h'-write: k=j -> e=wid, kt=l15>>2, g'=l15&3 -> byte l15*16 + 2*wid
    const int woff = g * 256 + ((l15 * 16 + 2 * wid) ^ (g << 5));

    for (int idx = tid; idx < SPB * HID; idx += NT)   // both parities (u32)
        ((uint32_t*)hbuf)[idx] = 0;
    __syncthreads();

    // A-frags zeroed once; masked loads keep inactive lanes at zero.
    u32x4 A_[4];
    #pragma unroll
    for (int kt = 0; kt < 4; ++kt) A_[kt] = (u32x4){0, 0, 0, 0};

    // ================= teacher-forced loop =================
    #pragma unroll 2
    for (int i = 0; i < TLEN; ++i) {
        const int p = i & 1;

        if ((i & 127) == 0) {         // refill x chunk (512 thr = 1 pass)
            const int t = tid & 127, s = tid >> 7;
            xstg[t][s] = x[(size_t)(s0 + s) * TLEN + (i + t)];
            __syncthreads();
        }
        if (i > 64 && (i & 63) == 1 && tid < 16 * SPB) {   // flush o ring
            const int q = ((i - 65) >> 6) & 1;
            const int s = tid >> 4, c4 = (tid & 15) * 4;
            const f32x4 v = *(const f32x4*)&ring[q][s][c4];
            *(f32x4*)&out[(size_t)(s0 + s) * NSTEP + (i - 65) + c4] = v;
        }

        const char* hb = (const char*)hbuf[p];
        if ((l15 & 3) == 0) {
            #pragma unroll
            for (int kt = 0; kt < 4; ++kt)
                A_[kt] = *(const u32x4*)(hb + aoff[kt]);
        }

        // 8 MFMA uniform: 4 S + 4 o
        f32x4 sA = {0.f,0.f,0.f,0.f}, ov = sA;
        #pragma unroll
        for (int kt = 0; kt < 4; ++kt) {
            sA = __builtin_amdgcn_mfma_f32_16x16x32_f16(asf16(A_[kt]), W0[kt], sA, 0, 0, 0);
            ov = __builtin_amdgcn_mfma_f32_16x16x32_f16(asf16(A_[kt]), Wo[kt], ov, 0, 0, 0);
        }

        // o_{i-1}[sample g] at wave-0 lanes l15==0 (C row 4g, col 0)
        if (i > 0 && wid == 0 && l15 == 0)
            ring[((i - 1) >> 6) & 1][g][(i - 1) & 63] = ov[0] + bo;

        const float in = xstg[i & 127][g];
        const float h0 = fast_tanh(sA[0] + bias0 + in * wih0);
        *(unsigned short*)((char*)hbuf[p ^ 1] + woff) =
            __builtin_bit_cast(unsigned short, (_Float16)h0);

        __syncthreads();
    }

    // ================= autoregressive loop =================
    #pragma unroll 2
    for (int i = TLEN; i < NSTEP; ++i) {
        const int p = i & 1;

        if ((i & 63) == 1 && tid < 16 * SPB) {   // flush (fires at i=1025)
            const int q = ((i - 65) >> 6) & 1;
            const int s = tid >> 4, c4 = (tid & 15) * 4;
            const f32x4 v = *(const f32x4*)&ring[q][s][c4];
            *(f32x4*)&out[(size_t)(s0 + s) * NSTEP + (i - 65) + c4] = v;
        }

        const char* hb = (const char*)hbuf[p];
        if ((l15 & 3) == 0) {
            #pragma unroll
            for (int kt = 0; kt < 4; ++kt)
                A_[kt] = *(const u32x4*)(hb + aoff[kt]);
        }

        f32x4 sA = {0.f,0.f,0.f,0.f}, ov = sA;
        #pragma unroll
        for (int kt = 0; kt < 4; ++kt) {
            sA = __builtin_amdgcn_mfma_f32_16x16x32_f16(asf16(A_[kt]), W0[kt], sA, 0, 0, 0);
            ov = __builtin_amdgcn_mfma_f32_16x16x32_f16(asf16(A_[kt]), Wo[kt], ov, 0, 0, 0);
        }
        const float oval = ov[0] + bo;          // valid at lanes l15==0
        if (wid == 0 && l15 == 0)
            ring[((i - 1) >> 6) & 1][g][(i - 1) & 63] = oval;

        // feedback: sample g's o sits at lane g*16 (l15==0 of group g)
        const float in = __shfl(oval, g << 4);
        const float h0 = fast_tanh(sA[0] + bias0 + in * wih0);
        *(unsigned short*)((char*)hbuf[p ^ 1] + woff) =
            __builtin_bit_cast(unsigned short, (_Float16)h0);

        __syncthreads();
    }

    // tail: o_{NSTEP-1} = wout . h_{NSTEP} (state in hbuf[NSTEP&1] = [0])
    {
        const char* hb = (const char*)hbuf[NSTEP & 1];
        if ((l15 & 3) == 0) {
            #pragma unroll
            for (int kt = 0; kt < 4; ++kt)
                A_[kt] = *(const u32x4*)(hb + aoff[kt]);
        }
        f32x4 ov = {0.f,0.f,0.f,0.f};
        #pragma unroll
        for (int kt = 0; kt < 4; ++kt)
            ov = __builtin_amdgcn_mfma_f32_16x16x32_f16(asf16(A_[kt]), Wo[kt], ov, 0, 0, 0);
        if (wid == 0 && l15 == 0)
            ring[0][g][63] = ov[0] + bo;        // (1087>>6)&1 = 0
    }
    __syncthreads();
    if (tid < 16 * SPB) {   // flush t = 1024..1087 (ring parity 0)
        const int s = tid >> 4, c4 = (tid & 15) * 4;
        const f32x4 v = *(const f32x4*)&ring[0][s][c4];
        *(f32x4*)&out[(size_t)(s0 + s) * NSTEP + TLEN + c4] = v;
    }
}

extern "C" void kernel_launch(void* const* d_in, const int* in_sizes, int n_in,
                              void* d_out, int out_size, void* d_ws, size_t ws_size,
                              hipStream_t stream) {
    const float* x     = (const float*)d_in[0];
    const float* W_ih  = (const float*)d_in[1];
    const float* W_hh  = (const float*)d_in[2];
    const float* b_ih  = (const float*)d_in[3];
    const float* b_hh  = (const float*)d_in[4];
    const float* W_out = (const float*)d_in[5];
    const float* b_out = (const float*)d_in[6];
    float* out = (float*)d_out;

    dim3 grid(2048 / SPB);   // 512 blocks -> 2 per CU, all resident
    dim3 block(NT);
    rnn_kernel<<<grid, block, 0, stream>>>(x, W_ih, W_hh, b_ih, b_hh,
                                           W_out, b_out, out);
}